// Round 1
// 392.354 us; speedup vs baseline: 1.1575x; 1.1575x over previous
//
#include <hip/hip_runtime.h>
#include <cmath>

#define D 64
#define SCAN_CHUNK 1024   // elements per scan block
#define PA_EDGES 4096     // edges per partition block
#define PB_CAP   8192     // LDS csr staging capacity per bucket (avg ~4096, 6-sigma safe)
#define MAXBUCK  512      // supports N <= 131072 (bucket = 256 nodes)

// ---------------------------------------------------------------------------
// CSR build step 1: histogram of dst + exclusive scan -> rowStart. Unchanged.
// ---------------------------------------------------------------------------
__global__ void hist_kernel(const int* __restrict__ dst, int* __restrict__ cnt, int E) {
    int t = blockIdx.x * blockDim.x + threadIdx.x;
    if (t < E) atomicAdd(&cnt[dst[t]], 1);
}

__global__ void block_sums_kernel(const int* __restrict__ cnt, int* __restrict__ bsum, int n) {
    __shared__ int red[256];
    int base = blockIdx.x * SCAN_CHUNK;
    int s = 0;
    for (int i = threadIdx.x; i < SCAN_CHUNK; i += 256) {
        int idx = base + i;
        s += (idx < n) ? cnt[idx] : 0;
    }
    red[threadIdx.x] = s;
    __syncthreads();
    for (int off = 128; off > 0; off >>= 1) {
        if (threadIdx.x < off) red[threadIdx.x] += red[threadIdx.x + off];
        __syncthreads();
    }
    if (threadIdx.x == 0) bsum[blockIdx.x] = red[0];
}

__global__ void scan_bsums_kernel(int* __restrict__ bsum, int nb) {
    __shared__ int s[256];
    int t = threadIdx.x;
    s[t] = (t < nb) ? bsum[t] : 0;
    __syncthreads();
    for (int off = 1; off < 256; off <<= 1) {
        int u = (t >= off) ? s[t - off] : 0;
        __syncthreads();
        s[t] += u;
        __syncthreads();
    }
    if (t < nb) bsum[t] = (t == 0) ? 0 : s[t - 1];   // exclusive
}

__global__ void scan_final_kernel(const int* __restrict__ cnt, const int* __restrict__ bsum,
                                  int* __restrict__ rowStart, int n, int E) {
    __shared__ int red[256];
    int t = threadIdx.x;
    int idx = blockIdx.x * SCAN_CHUNK + t * 4;
    int v0 = (idx + 0 < n) ? cnt[idx + 0] : 0;
    int v1 = (idx + 1 < n) ? cnt[idx + 1] : 0;
    int v2 = (idx + 2 < n) ? cnt[idx + 2] : 0;
    int v3 = (idx + 3 < n) ? cnt[idx + 3] : 0;
    red[t] = v0 + v1 + v2 + v3;
    __syncthreads();
    for (int off = 1; off < 256; off <<= 1) {
        int u = (t >= off) ? red[t - off] : 0;
        __syncthreads();
        red[t] += u;
        __syncthreads();
    }
    int excl = ((t == 0) ? 0 : red[t - 1]) + bsum[blockIdx.x];
    if (idx + 0 < n) rowStart[idx + 0] = excl;
    if (idx + 1 < n) rowStart[idx + 1] = excl + v0;
    if (idx + 2 < n) rowStart[idx + 2] = excl + v0 + v1;
    if (idx + 3 < n) rowStart[idx + 3] = excl + v0 + v1 + v2;
    if (blockIdx.x == 0 && t == 0) rowStart[n] = E;
}

// ---------------------------------------------------------------------------
// CSR build step 2 (NEW): bucketed fill to kill scattered-store write
// amplification (old fill_csr: 107 MB WRITE_SIZE for a 6.4 MB array).
// Bucket b = dst in [b*256, (b+1)*256); its csr region is
// [rowStart[b*256], rowStart[(b+1)*256]) -- bases come free from rowStart.
// ---------------------------------------------------------------------------
__global__ __launch_bounds__(256)
void cursor_init_kernel(const int* __restrict__ rowStart, int* __restrict__ cursor,
                        int n, int nbuck) {
    int b = blockIdx.x * blockDim.x + threadIdx.x;
    if (b < nbuck) cursor[b] = rowStart[min(b << 8, n)];
}

// Pass A: LDS-staged radix partition of (src,dst) pairs into bucket-contiguous
// segments of `pairs`. Random 8B scatters happen in LDS; global writes are
// ~10-edge (84B) contiguous segments.
__global__ __launch_bounds__(256)
void partition_kernel(const int* __restrict__ src, const int* __restrict__ dst,
                      int* __restrict__ cursor, uint2* __restrict__ pairs,
                      int E, int nbuck) {
    __shared__ int lhist[MAXBUCK];       // counts, then local fill cursors
    __shared__ int lbase[MAXBUCK + 1];   // local exclusive scan
    __shared__ int gbase[MAXBUCK];       // reserved global positions
    __shared__ int red[256];
    __shared__ uint2 stage[PA_EDGES];    // 32 KB

    const int t = threadIdx.x;
    const int e0 = blockIdx.x * PA_EDGES;
    const int ecnt = min(PA_EDGES, E - e0);

    lhist[t] = 0; lhist[t + 256] = 0;
    __syncthreads();
    for (int i = t; i < ecnt; i += 256) atomicAdd(&lhist[dst[e0 + i] >> 8], 1);
    __syncthreads();

    // exclusive scan over 512 padded entries: each thread owns 2 slots
    const int c0 = lhist[2 * t], c1 = lhist[2 * t + 1];
    red[t] = c0 + c1;
    __syncthreads();
    for (int off = 1; off < 256; off <<= 1) {
        int u = (t >= off) ? red[t - off] : 0;
        __syncthreads();
        red[t] += u;
        __syncthreads();
    }
    const int excl = (t == 0) ? 0 : red[t - 1];
    lbase[2 * t]     = excl;
    lbase[2 * t + 1] = excl + c0;
    if (t == 255) lbase[MAXBUCK] = red[255];
    // reserve global space per non-empty bucket
    for (int b = t; b < nbuck; b += 256) {
        const int c = lhist[b];
        gbase[b] = c ? atomicAdd(&cursor[b], c) : 0;
    }
    __syncthreads();
    lhist[t] = 0; lhist[t + 256] = 0;    // reuse as fill cursors
    __syncthreads();
    // bucket-ordered scatter into LDS stage
    for (int i = t; i < ecnt; i += 256) {
        const int d = dst[e0 + i];
        const int b = d >> 8;
        const int p = lbase[b] + atomicAdd(&lhist[b], 1);
        stage[p] = make_uint2((unsigned)src[e0 + i], (unsigned)d);
    }
    __syncthreads();
    // coalesced-segment write-out; bucket of slot i via upper_bound(lbase)-1
    for (int i = t; i < ecnt; i += 256) {
        int lo = 0, hi = MAXBUCK;
        while (hi - lo > 1) {
            const int mid = (lo + hi) >> 1;
            if (lbase[mid] <= i) lo = mid; else hi = mid;
        }
        pairs[gbase[lo] + (i - lbase[lo])] = stage[i];
    }
}

// Pass B: one block per bucket; build the bucket's csr slice entirely in LDS
// (random writes stay on-chip), then stream it out coalesced.
__global__ __launch_bounds__(256)
void bucket_fill_kernel(const uint2* __restrict__ pairs, const int* __restrict__ rowStart,
                        int* __restrict__ fill, int* __restrict__ csr, int n) {
    __shared__ int lcsr[PB_CAP];         // 32 KB
    __shared__ int lrow[257];
    __shared__ int lfill[256];
    const int t = threadIdx.x;
    const int node0 = blockIdx.x << 8;
    const int node1 = min(node0 + 256, n);
    lrow[t] = rowStart[min(node0 + t, n)];
    if (t == 0) lrow[256] = rowStart[node1];
    lfill[t] = 0;
    __syncthreads();
    const int base = lrow[0];
    const int cntE = lrow[256] - base;
    if (cntE <= PB_CAP) {
        for (int i = t; i < cntE; i += 256) {
            const uint2 pr = pairs[base + i];
            const int d = (int)pr.y;
            const int p = lrow[d - node0] - base + atomicAdd(&lfill[d - node0], 1);
            lcsr[p] = (int)pr.x;
        }
        __syncthreads();
        for (int i = t; i < cntE; i += 256) csr[base + i] = lcsr[i];
    } else {   // safety fallback (never triggers for uniform-random dst)
        for (int i = t; i < cntE; i += 256) {
            const uint2 pr = pairs[base + i];
            const int d = (int)pr.y;
            const int p = rowStart[d] + atomicAdd(&fill[d], 1);
            csr[p] = (int)pr.x;
        }
    }
}

// ---------------------------------------------------------------------------
// Dual register-column matmul: outA = x@Wa ; outB = x@Wb + bias.
// Reads each input row ONCE for both products (was two kernels).
// 128 weight VGPRs + 8 accumulators -> ~150 VGPR, 3 waves/EU.
// ---------------------------------------------------------------------------
__global__ __launch_bounds__(256, 3)
void matmul2_kernel(const float* __restrict__ xin,
                    const float* __restrict__ Wa,
                    const float* __restrict__ Wb,
                    const float* __restrict__ bias,
                    float* __restrict__ outA,
                    float* __restrict__ outB,
                    int n) {
    const int lane = threadIdx.x & 63;
    const int wave = threadIdx.x >> 6;
    const int gw = blockIdx.x * 4 + wave;
    const int nw = gridDim.x * 4;

    float wa[D], wb[D];
#pragma unroll
    for (int k = 0; k < D; ++k) wa[k] = Wa[k * D + lane];   // column `lane`
#pragma unroll
    for (int k = 0; k < D; ++k) wb[k] = Wb[k * D + lane];
    const float bv = bias[lane];

    for (int node = gw; node < n; node += nw) {
        const float xl = xin[(size_t)node * D + lane];
        const unsigned xu = __float_as_uint(xl);
        float a0 = 0, a1 = 0, a2 = 0, a3 = 0;
        float b0 = bv, b1 = 0, b2 = 0, b3 = 0;
#pragma unroll
        for (int k = 0; k < D; k += 4) {
            const float s0 = __uint_as_float(__builtin_amdgcn_readlane(xu, k + 0));
            const float s1 = __uint_as_float(__builtin_amdgcn_readlane(xu, k + 1));
            const float s2 = __uint_as_float(__builtin_amdgcn_readlane(xu, k + 2));
            const float s3 = __uint_as_float(__builtin_amdgcn_readlane(xu, k + 3));
            a0 = fmaf(s0, wa[k + 0], a0); b0 = fmaf(s0, wb[k + 0], b0);
            a1 = fmaf(s1, wa[k + 1], a1); b1 = fmaf(s1, wb[k + 1], b1);
            a2 = fmaf(s2, wa[k + 2], a2); b2 = fmaf(s2, wb[k + 2], b2);
            a3 = fmaf(s3, wa[k + 3], a3); b3 = fmaf(s3, wb[k + 3], b3);
        }
        outA[(size_t)node * D + lane] = (a0 + a1) + (a2 + a3);
        outB[(size_t)node * D + lane] = (b0 + b1) + (b2 + b3);
    }
}

// ---------------------------------------------------------------------------
// Gather-mean aggregation: h = ELU(sum(u[nbrs])/deg + v). One wave per node,
// no LDS. CSR indices fetched 8-at-a-time via one broadcast load + readlane.
// FUSE_FINAL: out = h @ Wf + bf with Wf column register-resident. Unchanged.
// ---------------------------------------------------------------------------
template <bool FUSE_FINAL>
__global__ __launch_bounds__(256, 4)
void agg_kernel(const float* __restrict__ u,
                const float* __restrict__ v,
                const int* __restrict__ rowStart,
                const int* __restrict__ csr,
                const float* __restrict__ Wf,
                const float* __restrict__ bf,
                float* __restrict__ out,
                int n) {
    const int lane = threadIdx.x & 63;
    const int wave = threadIdx.x >> 6;
    const int gw = blockIdx.x * (blockDim.x >> 6) + wave;
    const int nw = gridDim.x * (blockDim.x >> 6);

    float wf[FUSE_FINAL ? D : 1];
    float bias2 = 0.0f;
    if (FUSE_FINAL) {
#pragma unroll
        for (int k = 0; k < D; ++k) wf[k] = Wf[k * D + lane];   // Wf column `lane`
        bias2 = bf[lane];
    }

    for (int node = gw; node < n; node += nw) {
        const int r0 = rowStart[node];
        const int r1 = rowStart[node + 1];

        float a0 = 0, a1 = 0, a2 = 0, a3 = 0, a4 = 0, a5 = 0, a6 = 0, a7 = 0;
        int j = r0;
        for (; j + 8 <= r1; j += 8) {
            const int c = csr[j + (lane & 7)];                    // broadcast 32B
            const int s0 = __builtin_amdgcn_readlane(c, 0);
            const int s1 = __builtin_amdgcn_readlane(c, 1);
            const int s2 = __builtin_amdgcn_readlane(c, 2);
            const int s3 = __builtin_amdgcn_readlane(c, 3);
            const int s4 = __builtin_amdgcn_readlane(c, 4);
            const int s5 = __builtin_amdgcn_readlane(c, 5);
            const int s6 = __builtin_amdgcn_readlane(c, 6);
            const int s7 = __builtin_amdgcn_readlane(c, 7);
            a0 += u[(size_t)s0 * D + lane];
            a1 += u[(size_t)s1 * D + lane];
            a2 += u[(size_t)s2 * D + lane];
            a3 += u[(size_t)s3 * D + lane];
            a4 += u[(size_t)s4 * D + lane];
            a5 += u[(size_t)s5 * D + lane];
            a6 += u[(size_t)s6 * D + lane];
            a7 += u[(size_t)s7 * D + lane];
        }
        if (j + 4 <= r1) {
            const int c = csr[j + (lane & 3)];
            const int s0 = __builtin_amdgcn_readlane(c, 0);
            const int s1 = __builtin_amdgcn_readlane(c, 1);
            const int s2 = __builtin_amdgcn_readlane(c, 2);
            const int s3 = __builtin_amdgcn_readlane(c, 3);
            a0 += u[(size_t)s0 * D + lane];
            a1 += u[(size_t)s1 * D + lane];
            a2 += u[(size_t)s2 * D + lane];
            a3 += u[(size_t)s3 * D + lane];
            j += 4;
        }
        for (; j < r1; ++j) {
            const int s = csr[j];
            a4 += u[(size_t)s * D + lane];
        }

        const float deg = (float)(r1 - r0);
        const float sum = ((a0 + a1) + (a2 + a3)) + ((a4 + a5) + (a6 + a7));
        float h = sum / fmaxf(deg, 1.0f) + v[(size_t)node * D + lane];
        h = h > 0.0f ? h : expm1f(h);   // ELU(alpha=1)

        if (FUSE_FINAL) {
            float o = bias2;
#pragma unroll
            for (int k = 0; k < D; ++k) {
                const float hk =
                    __uint_as_float(__builtin_amdgcn_readlane(__float_as_uint(h), k));
                o = fmaf(hk, wf[k], o);
            }
            out[(size_t)node * D + lane] = o;
        } else {
            out[(size_t)node * D + lane] = h;
        }
    }
}

extern "C" void kernel_launch(void* const* d_in, const int* in_sizes, int n_in,
                              void* d_out, int out_size, void* d_ws, size_t ws_size,
                              hipStream_t stream) {
    const float* x    = (const float*)d_in[0];
    const int*   ei   = (const int*)d_in[1];
    const float* W1l  = (const float*)d_in[2];
    const float* b1   = (const float*)d_in[3];
    const float* W1r  = (const float*)d_in[4];
    const float* W2l  = (const float*)d_in[5];
    const float* b2   = (const float*)d_in[6];
    const float* W2r  = (const float*)d_in[7];
    const float* Wlin = (const float*)d_in[8];
    const float* blin = (const float*)d_in[9];

    const int N_ = in_sizes[0] / D;      // 100000
    const int E_ = in_sizes[1] / 2;      // 1600000
    const int* src = ei;
    const int* dst = ei + E_;

    // workspace layout
    int* cnt      = (int*)d_ws;                 // N
    int* fill     = cnt + N_;                   // N   (adjacent -> one memset)
    int* rowStart = fill + N_;                  // N+1
    int* bsum     = rowStart + N_ + 1;          // 256
    int* cursor   = bsum + 256;                 // MAXBUCK
    int* csr      = cursor + MAXBUCK;           // E
    size_t ofs = (size_t)((csr + E_) - (int*)d_ws);
    ofs = (ofs + 3) & ~(size_t)3;               // 16B-align float region
    float* ubuf   = (float*)d_ws + ofs;         // N*64
    float* vbuf   = ubuf + (size_t)N_ * D;      // N*64
    float* hbuf   = vbuf + (size_t)N_ * D;      // N*64 (h1)
    // pairs buffer (E * 8B = 12.8 MB) aliases ubuf (25.6 MB): consumed by
    // bucket_fill BEFORE matmul2 first writes ubuf (same stream -> ordered).
    uint2* pairs  = (uint2*)ubuf;

    const int nb    = (N_ + SCAN_CHUNK - 1) / SCAN_CHUNK;   // 98
    const int nbuck = (N_ + 255) >> 8;                      // 391

    hipMemsetAsync(cnt, 0, (size_t)2 * N_ * sizeof(int), stream);  // cnt + fill

    hist_kernel<<<(E_ + 255) / 256, 256, 0, stream>>>(dst, cnt, E_);
    block_sums_kernel<<<nb, 256, 0, stream>>>(cnt, bsum, N_);
    scan_bsums_kernel<<<1, 256, 0, stream>>>(bsum, nb);
    scan_final_kernel<<<nb, 256, 0, stream>>>(cnt, bsum, rowStart, N_, E_);
    cursor_init_kernel<<<(nbuck + 255) / 256, 256, 0, stream>>>(rowStart, cursor, N_, nbuck);
    partition_kernel<<<(E_ + PA_EDGES - 1) / PA_EDGES, 256, 0, stream>>>(
        src, dst, cursor, pairs, E_, nbuck);
    bucket_fill_kernel<<<nbuck, 256, 0, stream>>>(pairs, rowStart, fill, csr, N_);

    // Layer 1: u1 = x@W1l ; v1 = x@W1r + b1  (one pass over x)
    matmul2_kernel<<<2048, 256, 0, stream>>>(x, W1l, W1r, b1, ubuf, vbuf, N_);
    // h1 = ELU(mean(u1)+v1)
    agg_kernel<false><<<2048, 256, 0, stream>>>(ubuf, vbuf, rowStart, csr,
                                                nullptr, nullptr, hbuf, N_);
    // Layer 2: u2 = h1@W2l ; v2 = h1@W2r + b2  (one pass over h1)
    matmul2_kernel<<<2048, 256, 0, stream>>>(hbuf, W2l, W2r, b2, ubuf, vbuf, N_);
    // h2 = ELU(mean(u2)+v2), fused out = h2@Wlin + blin
    agg_kernel<true><<<2048, 256, 0, stream>>>(ubuf, vbuf, rowStart, csr,
                                               Wlin, blin, (float*)d_out, N_);
}